// Round 15
// baseline (343.158 us; speedup 1.0000x reference)
//
#include <hip/hip_runtime.h>

#define NN 100000
#define NE 1600000

#define EBLK 2048
#define NBLK 782            // ceil(NE/EBLK)
#define NBUCK 196           // ceil(NN/512), bucket = dst>>9
#define GEMM_BLOCKS 1563    // ceil(NN/64)
#define FINX_BLOCKS 6250    // NN/16
#define AGG_BLOCKS 3125     // 32 nodes per block (8 per wave)

typedef unsigned int uint32;
typedef __attribute__((ext_vector_type(8))) short bf16x8;
typedef __attribute__((ext_vector_type(4))) float f32x4;

#define QDS (1.0f / 32767.0f)

__device__ inline unsigned short f2bf(float f) {
    uint32 u = __float_as_uint(f);
    u += 0x7FFFu + ((u >> 16) & 1u);      // round to nearest even
    return (unsigned short)(u >> 16);
}
__device__ inline float bflo(uint32 v) { return __uint_as_float(v << 16); }
__device__ inline float bfhi(uint32 v) { return __uint_as_float(v & 0xFFFF0000u); }
__device__ inline uint32 packbf(float a, float b) {
    return (uint32)f2bf(a) | ((uint32)f2bf(b) << 16);
}

__device__ inline int wave_incl_scan(int v) {   // 64-lane inclusive scan
#pragma unroll
    for (int d = 1; d < 64; d <<= 1) {
        int u = __shfl_up(v, d, 64);
        if ((threadIdx.x & 63) >= (unsigned)d) v += u;
    }
    return v;
}

// -------- W prep (both weights): Wt[col][k] bf16-packed (tiny pre-kernel) --

__global__ __launch_bounds__(256) void wprep_k(const float* __restrict__ W1,
                                               const float* __restrict__ W2,
                                               uint32* __restrict__ wt1,
                                               uint32* __restrict__ wt2) {
    int id = blockIdx.x * 256 + threadIdx.x;   // 16384
    const float* W = (id < 8192) ? W1 : W2;
    uint32* Wt = (id < 8192) ? wt1 : wt2;
    int i = id & 8191;
    int col = i >> 6, ku = i & 63;
    float a = W[(2 * ku) * 128 + col];
    float b = W[(2 * ku + 1) * 128 + col];
    Wt[i] = packbf(a, b);
}

// ---------------- GEMM body: HS[N,128](bf16) = act(X) @ Wt (UNSCALED) ------
// AFF=0: X f32 [N,128]. AFF=1: X packed bf16; GraphNorm par from stats.
// Block: 256 thr / 4 waves, tile 64 rows x 128 cols, K=128 in 4 steps of 32.
// LDS: A [64][136] bf16 (17408 B) + Bt [128][136] bf16 (34816 B) = 52224 B.

template <int AFF>
__device__ __forceinline__ void gemm_body(int bid, const void* __restrict__ Xv,
                                          const uint32* __restrict__ Wt,
                                          const float* __restrict__ stats,
                                          const float* __restrict__ gw,
                                          const float* __restrict__ gb,
                                          const float* __restrict__ ga,
                                          uint32* __restrict__ HS,
                                          char* lds, float* parL) {
    const int APITCH = 272;               // bytes per A/B row (136 bf16)
    char* Ab = lds;
    char* Bb = lds + 17408;
    int t = threadIdx.x;
    int row0 = bid * 64;

    if (AFF) {
        if (t < 128) {
            float m = stats[t] * (1.0f / NN);
            float ex2 = stats[128 + t] * (1.0f / NN);
            float ac = ga[t];
            float var = ex2 - 2.0f * ac * m * m + ac * ac * m * m;
            float sc = gw[t] * rsqrtf(var + 1e-5f);
            parL[t] = sc;
            parL[128 + t] = gb[t] - sc * ac * m;
        }
        __syncthreads();
    }

    // stage Bt: 128 rows x 16 uint4 (packed bf16 Wt)
    {
        uint4* src = (uint4*)Wt;
#pragma unroll
        for (int i = 0; i < 8; ++i) {
            int idx4 = i * 256 + t;          // 2048 uint4
            int r = idx4 >> 4, cu = idx4 & 15;
            *(uint4*)(Bb + r * APITCH + cu * 16) = src[r * 16 + cu];
        }
    }
    // stage A: 64 rows x 128 bf16
#pragma unroll
    for (int i = 0; i < 8; ++i) {
        int idx = i * 256 + t;               // 2048 quads of channels
        int r = idx >> 5, c4 = idx & 31;
        int row = row0 + r;
        float4 v = make_float4(0.f, 0.f, 0.f, 0.f);
        if (row < NN) {
            if (AFF) {
                uint2 u = *((const uint2*)((const uint32*)Xv + (size_t)row * 64) + c4);
                v.x = bflo(u.x); v.y = bfhi(u.x);
                v.z = bflo(u.y); v.w = bfhi(u.y);
                int c = c4 * 4;
                v.x = fmaxf(0.f, fmaf(parL[c + 0], v.x, parL[128 + c + 0]));
                v.y = fmaxf(0.f, fmaf(parL[c + 1], v.y, parL[128 + c + 1]));
                v.z = fmaxf(0.f, fmaf(parL[c + 2], v.z, parL[128 + c + 2]));
                v.w = fmaxf(0.f, fmaf(parL[c + 3], v.w, parL[128 + c + 3]));
            } else {
                v = *((const float4*)((const float*)Xv + (size_t)row * 128) + c4);
            }
        }
        uint2 o;
        o.x = packbf(v.x, v.y);
        o.y = packbf(v.z, v.w);
        *(uint2*)(Ab + r * APITCH + c4 * 8) = o;
    }
    __syncthreads();

    int w = t >> 6, lane = t & 63;
    int l15 = lane & 15, l4 = lane >> 4;
    const char* aptr = Ab + (w * 16 + l15) * APITCH + l4 * 16;
    const char* bptr = Bb + l15 * APITCH + l4 * 16;
    f32x4 acc[8];
#pragma unroll
    for (int n = 0; n < 8; ++n)
#pragma unroll
        for (int j = 0; j < 4; ++j) acc[n][j] = 0.f;

#pragma unroll
    for (int ks = 0; ks < 4; ++ks) {
        bf16x8 a = *(const bf16x8*)(aptr + ks * 64);
#pragma unroll
        for (int n = 0; n < 8; ++n) {
            bf16x8 b = *(const bf16x8*)(bptr + n * 16 * APITCH + ks * 64);
            acc[n] = __builtin_amdgcn_mfma_f32_16x16x32_bf16(a, b, acc[n], 0, 0, 0);
        }
    }

    // epilogue: bf16 -> LDS (reuse A region) -> coalesced store
    unsigned short* ep = (unsigned short*)Ab;
#pragma unroll
    for (int n = 0; n < 8; ++n)
#pragma unroll
        for (int j = 0; j < 4; ++j)
            ep[(w * 16 + l4 * 4 + j) * 136 + n * 16 + l15] = f2bf(acc[n][j]);
    __syncthreads();
    int srow = lane >> 2, seg = lane & 3;
    int grow = row0 + w * 16 + srow;
    if (grow < NN) {
        const char* lp = Ab + (w * 16 + srow) * APITCH + seg * 64;
        uint4* gp = (uint4*)(HS + (size_t)grow * 64 + seg * 16);
#pragma unroll
        for (int i = 0; i < 4; ++i)
            gp[i] = *(const uint4*)(lp + i * 16);
    }
}

// ---- phase 1 (3 roles): GEMM1 (1563) ∥ hist (782) ∥ head-x (6250) --------
// All independent: gemm1 reads x,wt1 -> bufH (unscaled);
// hist reads dst -> histT; head-x reads x,Wh,bh -> out.

__global__ __launch_bounds__(256) void phase1_k(const int* __restrict__ dst,
                                                int* __restrict__ histT,
                                                const float* __restrict__ X,
                                                const uint32* __restrict__ wt1,
                                                uint32* __restrict__ HS,
                                                const float* __restrict__ Wh,
                                                const float* __restrict__ bh,
                                                float* __restrict__ out) {
    __shared__ __align__(16) char lds[52224];
    int t = threadIdx.x;
    if (blockIdx.x < GEMM_BLOCKS) {
        gemm_body<0>(blockIdx.x, X, wt1, nullptr, nullptr, nullptr, nullptr,
                     HS, lds, nullptr);
    } else if (blockIdx.x < GEMM_BLOCKS + NBLK) {
        int* h = (int*)lds;
        h[t] = 0;
        __syncthreads();
        int e0 = (blockIdx.x - GEMM_BLOCKS) * EBLK;
#pragma unroll
        for (int i = 0; i < EBLK / 256; ++i) {
            int e = e0 + i * 256 + t;
            if (e < NE) atomicAdd(&h[dst[e] >> 9], 1);
        }
        __syncthreads();
        histT[t * NBLK + (blockIdx.x - GEMM_BLOCKS)] = h[t];   // histT[bucket][blk]
    } else {
        // head x-half: out[row,o] = bh[o] + sum_k x[row,k] * Wh[k][o]
        int bid = blockIdx.x - GEMM_BLOCKS - NBLK;
        float (*wl)[16] = (float(*)[16])lds;   // 128 x 16
        for (int i = t; i < 128 * 16; i += 256) wl[i >> 4][i & 15] = Wh[i];
        __syncthreads();
        int row = bid * 16 + (t >> 4);         // 6250*16 == NN exactly
        int o = t & 15;
        const float4* xp = (const float4*)(X + (size_t)row * 128);
        float acc = bh[o];
#pragma unroll
        for (int k4 = 0; k4 < 32; ++k4) {
            float4 v = xp[k4];
            acc = fmaf(v.x, wl[k4 * 4 + 0][o], acc);
            acc = fmaf(v.y, wl[k4 * 4 + 1][o], acc);
            acc = fmaf(v.z, wl[k4 * 4 + 2][o], acc);
            acc = fmaf(v.w, wl[k4 * 4 + 3][o], acc);
        }
        out[(size_t)row * 16 + o] = acc;
    }
}

// ---------------- GEMM2 (standalone): gn1+relu fused, UNSCALED output ------

__global__ __launch_bounds__(256) void gemm2_k(const uint32* __restrict__ Xv,
                                               const uint32* __restrict__ Wt,
                                               const float* __restrict__ stats,
                                               const float* __restrict__ gw,
                                               const float* __restrict__ gb,
                                               const float* __restrict__ ga,
                                               uint32* __restrict__ HS) {
    __shared__ __align__(16) char lds[52224];
    __shared__ float parL[256];
    gemm_body<1>(blockIdx.x, Xv, Wt, stats, gw, gb, ga, HS, lds, parL);
}

// ---------------- CSR build scans ----------------

__global__ __launch_bounds__(256) void p2a_k(const int* __restrict__ histT,
                                             int* __restrict__ boff2,
                                             int* __restrict__ btot) {
    __shared__ int ws[4];
    int b = blockIdx.x, t = threadIdx.x;
    const int* row = histT + (size_t)b * NBLK;
    int run = 0;
    for (int base = 0; base < NBLK; base += 256) {
        int idx = base + t;
        int v = (idx < NBLK) ? row[idx] : 0;
        int incl = wave_incl_scan(v);
        if ((t & 63) == 63) ws[t >> 6] = incl;
        __syncthreads();
        int add = run;
        for (int w = 0; w < (t >> 6); ++w) add += ws[w];
        if (idx < NBLK) boff2[(size_t)b * NBLK + idx] = add + incl - v;
        run += ws[0] + ws[1] + ws[2] + ws[3];
        __syncthreads();
    }
    if (t == 0) btot[b] = run;
}

__global__ __launch_bounds__(256) void p2b_k(const int* __restrict__ btot,
                                             int* __restrict__ bucket_base,
                                             int* __restrict__ offs) {
    __shared__ int ws[4];
    int t = threadIdx.x;
    int v = btot[t];
    int incl = wave_incl_scan(v);
    if ((t & 63) == 63) ws[t >> 6] = incl;
    __syncthreads();
    int add = 0;
    for (int w = 0; w < (t >> 6); ++w) add += ws[w];
    int excl = incl - v + add;
    bucket_base[t] = excl;
    if (t == 255) bucket_base[256] = excl + v;   // == NE
    if (t == 0) offs[NN] = NE;
}

__global__ __launch_bounds__(256) void p3_scatter_k(const int* __restrict__ src,
                                                    const int* __restrict__ dst,
                                                    const int* __restrict__ boff2,
                                                    const int* __restrict__ bucket_base,
                                                    uint32* __restrict__ ebuf) {
    __shared__ int cur[256];
    int t = threadIdx.x;
    cur[t] = bucket_base[t] + boff2[(size_t)t * NBLK + blockIdx.x];
    __syncthreads();
    int e0 = blockIdx.x * EBLK;
#pragma unroll
    for (int i = 0; i < EBLK / 256; ++i) {
        int e = e0 + i * 256 + t;
        if (e < NE) {
            int d = dst[e];
            int pos = atomicAdd(&cur[d >> 9], 1);      // LDS atomic
            ebuf[pos] = ((uint32)(d & 511) << 17) | (uint32)src[e];
        }
    }
}

// P4a: per-bucket counts -> offs, dinv (no fill).

__global__ __launch_bounds__(256) void p4a_k(const uint32* __restrict__ ebuf,
                                             const int* __restrict__ bucket_base,
                                             int* __restrict__ offs,
                                             float* __restrict__ dinv) {
    __shared__ int cntL[512];
    __shared__ int wsum[4];
    int t = threadIdx.x;
    int bbase = bucket_base[blockIdx.x];
    int bend  = bucket_base[blockIdx.x + 1];
    cntL[t] = 0; cntL[t + 256] = 0;
    __syncthreads();
    for (int e = bbase + t; e < bend; e += 256)
        atomicAdd(&cntL[ebuf[e] >> 17], 1);
    __syncthreads();
    int c0 = cntL[2 * t], c1 = cntL[2 * t + 1];
    int ps = c0 + c1;
    int incl = wave_incl_scan(ps);
    if ((t & 63) == 63) wsum[t >> 6] = incl;
    __syncthreads();
    int add = 0;
    for (int w = 0; w < (t >> 6); ++w) add += wsum[w];
    int excl = incl - ps + add;
    int n0 = blockIdx.x * 512;
    int off0 = excl, off1 = excl + c0;
#pragma unroll
    for (int j = 0; j < 2; ++j) {
        int dl = 2 * t + j;
        int node = n0 + dl;
        if (node < NN) {
            offs[node] = bbase + (j ? off1 : off0);
            dinv[node] = rsqrtf((float)((j ? c1 : c0) + 1));
        }
    }
}

// P4b: fill csrc = src | q15(dinv[src])<<17 via LDS cursors from offs.

__global__ __launch_bounds__(256) void p4b_k(const uint32* __restrict__ ebuf,
                                             const int* __restrict__ bucket_base,
                                             const int* __restrict__ offs,
                                             const float* __restrict__ dinv,
                                             uint32* __restrict__ csrc) {
    __shared__ int cur[512];
    int t = threadIdx.x;
    int bbase = bucket_base[blockIdx.x];
    int bend  = bucket_base[blockIdx.x + 1];
    int n0 = blockIdx.x * 512;
#pragma unroll
    for (int j = 0; j < 2; ++j) {
        int dl = t + j * 256;
        int node = n0 + dl;
        cur[dl] = (node < NN) ? offs[node] : 0;
    }
    __syncthreads();
    int e = bbase + t;
    for (; e + 768 < bend; e += 1024) {
        uint32 v0 = ebuf[e], v1 = ebuf[e + 256], v2 = ebuf[e + 512], v3 = ebuf[e + 768];
        int s0 = v0 & 0x1FFFF, s1 = v1 & 0x1FFFF, s2 = v2 & 0x1FFFF, s3 = v3 & 0x1FFFF;
        float d0 = dinv[s0], d1 = dinv[s1], d2 = dinv[s2], d3 = dinv[s3];
        int p0 = atomicAdd(&cur[v0 >> 17], 1);
        int p1 = atomicAdd(&cur[v1 >> 17], 1);
        int p2 = atomicAdd(&cur[v2 >> 17], 1);
        int p3 = atomicAdd(&cur[v3 >> 17], 1);
        csrc[p0] = (uint32)s0 | ((uint32)(int)(d0 * 32767.0f + 0.5f) << 17);
        csrc[p1] = (uint32)s1 | ((uint32)(int)(d1 * 32767.0f + 0.5f) << 17);
        csrc[p2] = (uint32)s2 | ((uint32)(int)(d2 * 32767.0f + 0.5f) << 17);
        csrc[p3] = (uint32)s3 | ((uint32)(int)(d3 * 32767.0f + 0.5f) << 17);
    }
    for (; e < bend; e += 256) {
        uint32 v0 = ebuf[e];
        int s0 = v0 & 0x1FFFF;
        float d0 = dinv[s0];
        int p0 = atomicAdd(&cur[v0 >> 17], 1);
        csrc[p0] = (uint32)s0 | ((uint32)(int)(d0 * 32767.0f + 0.5f) << 17);
    }
}

// ---------------- edge aggregation + fused GraphNorm stats ----------------
// h UNSCALED; csrc packs src (17b) + q15(dinv[src]) (15b):
// out[i,c] = dinv[i]*( sum_e ds*h[src,c] + dinv[i]*h[i,c] ) + bias[c]
// One wave per node, 8 nodes sequentially per wave (32 nodes/block).
// Lane owns channels {2*lane, 2*lane+1}. 16-deep MLP unroll; ds decoded
// from the csrc word (no extra loads -> no VGPR blowup, cf. R13).

__global__ __launch_bounds__(256) void aggregate_k(const uint32* __restrict__ hv,
                                                   const int* __restrict__ offs,
                                                   const uint32* __restrict__ csrc,
                                                   const float* __restrict__ dinv,
                                                   const float* __restrict__ bias,
                                                   uint32* __restrict__ out,
                                                   float* __restrict__ pstats) {
    __shared__ float4 sh[256];
    int t = threadIdx.x;
    int w = t >> 6, lane = t & 63;
    int nbase = blockIdx.x * 32 + w * 8;
    float2 bb = ((const float2*)bias)[lane];
    float s0 = 0.f, s1 = 0.f, q0 = 0.f, q1 = 0.f;
#pragma unroll 1
    for (int i = 0; i < 8; ++i) {
        int node = nbase + i;
        int beg = offs[node], end = offs[node + 1];
        float di = dinv[node];
        uint32 sv = hv[(size_t)node * 64 + lane];   // self (unscaled)
        float a0 = di * bflo(sv), a1 = di * bfhi(sv);
        int e = beg;
        for (; e + 15 < end; e += 16) {
            uint32 x0 = csrc[e + 0], x1 = csrc[e + 1], x2 = csrc[e + 2], x3 = csrc[e + 3];
            uint32 x4 = csrc[e + 4], x5 = csrc[e + 5], x6 = csrc[e + 6], x7 = csrc[e + 7];
            uint32 x8 = csrc[e + 8], x9 = csrc[e + 9], xa = csrc[e + 10], xb = csrc[e + 11];
            uint32 xc = csrc[e + 12], xd = csrc[e + 13], xe = csrc[e + 14], xf = csrc[e + 15];
            uint32 v0 = hv[(size_t)(x0 & 0x1FFFF) * 64 + lane];
            uint32 v1 = hv[(size_t)(x1 & 0x1FFFF) * 64 + lane];
            uint32 v2 = hv[(size_t)(x2 & 0x1FFFF) * 64 + lane];
            uint32 v3 = hv[(size_t)(x3 & 0x1FFFF) * 64 + lane];
            uint32 v4 = hv[(size_t)(x4 & 0x1FFFF) * 64 + lane];
            uint32 v5 = hv[(size_t)(x5 & 0x1FFFF) * 64 + lane];
            uint32 v6 = hv[(size_t)(x6 & 0x1FFFF) * 64 + lane];
            uint32 v7 = hv[(size_t)(x7 & 0x1FFFF) * 64 + lane];
            uint32 v8 = hv[(size_t)(x8 & 0x1FFFF) * 64 + lane];
            uint32 v9 = hv[(size_t)(x9 & 0x1FFFF) * 64 + lane];
            uint32 va = hv[(size_t)(xa & 0x1FFFF) * 64 + lane];
            uint32 vb = hv[(size_t)(xb & 0x1FFFF) * 64 + lane];
            uint32 vc = hv[(size_t)(xc & 0x1FFFF) * 64 + lane];
            uint32 vd = hv[(size_t)(xd & 0x1FFFF) * 64 + lane];
            uint32 ve = hv[(size_t)(xe & 0x1FFFF) * 64 + lane];
            uint32 vf = hv[(size_t)(xf & 0x1FFFF) * 64 + lane];
            float d0 = (float)(x0 >> 17) * QDS, d1 = (float)(x1 >> 17) * QDS;
            float d2 = (float)(x2 >> 17) * QDS, d3 = (float)(x3 >> 17) * QDS;
            float d4 = (float)(x4 >> 17) * QDS, d5 = (float)(x5 >> 17) * QDS;
            float d6 = (float)(x6 >> 17) * QDS, d7 = (float)(x7 >> 17) * QDS;
            float d8 = (float)(x8 >> 17) * QDS, d9 = (float)(x9 >> 17) * QDS;
            float da = (float)(xa >> 17) * QDS, db = (float)(xb >> 17) * QDS;
            float dc = (float)(xc >> 17) * QDS, dd = (float)(xd >> 17) * QDS;
            float de = (float)(xe >> 17) * QDS, df = (float)(xf >> 17) * QDS;
            a0 += (((d0 * bflo(v0) + d1 * bflo(v1)) + (d2 * bflo(v2) + d3 * bflo(v3)))
                 + ((d4 * bflo(v4) + d5 * bflo(v5)) + (d6 * bflo(v6) + d7 * bflo(v7))))
                + (((d8 * bflo(v8) + d9 * bflo(v9)) + (da * bflo(va) + db * bflo(vb)))
                 + ((dc * bflo(vc) + dd * bflo(vd)) + (de * bflo(ve) + df * bflo(vf))));
            a1 += (((d0 * bfhi(v0) + d1 * bfhi(v1)) + (d2 * bfhi(v2) + d3 * bfhi(v3)))
                 + ((d4 * bfhi(v4) + d5 * bfhi(v5)) + (d6 * bfhi(v6) + d7 * bfhi(v7))))
                + (((d8 * bfhi(v8) + d9 * bfhi(v9)) + (da * bfhi(va) + db * bfhi(vb)))
                 + ((dc * bfhi(vc) + dd * bfhi(vd)) + (de * bfhi(ve) + df * bfhi(vf))));
        }
        for (; e + 3 < end; e += 4) {
            uint32 x0 = csrc[e + 0], x1 = csrc[e + 1], x2 = csrc[e + 2], x3 = csrc[e + 3];
            uint32 v0 = hv[(size_t)(x0 & 0x1FFFF) * 64 + lane];
            uint32 v1 = hv[(size_t)(x1 & 0x1FFFF) * 64 + lane];
            uint32 v2 = hv[(size_t)(x2 & 0x1FFFF) * 64 + lane];
            uint32 v3 = hv[(size_t)(x3 & 0x1FFFF) * 64 + lane];
            float d0 = (float)(x0 >> 17) * QDS, d1 = (float)(x1 >> 17) * QDS;
            float d2 = (float)(x2 >> 17) * QDS, d3 = (float)(x3 >> 17) * QDS;
            a0 += (d0 * bflo(v0) + d1 * bflo(v1)) + (d2 * bflo(v2) + d3 * bflo(v3));
            a1 += (d0 * bfhi(v0) + d1 * bfhi(v1)) + (d2 * bfhi(v2) + d3 * bfhi(v3));
        }
        for (; e < end; ++e) {
            uint32 x0 = csrc[e];
            uint32 v0 = hv[(size_t)(x0 & 0x1FFFF) * 64 + lane];
            float d0 = (float)(x0 >> 17) * QDS;
            a0 = fmaf(d0, bflo(v0), a0);
            a1 = fmaf(d0, bfhi(v0), a1);
        }
        float o0 = fmaf(di, a0, bb.x);
        float o1 = fmaf(di, a1, bb.y);
        out[(size_t)node * 64 + lane] = packbf(o0, o1);
        s0 += o0; s1 += o1;
        q0 = fmaf(o0, o0, q0); q1 = fmaf(o1, o1, q1);
    }
    sh[t] = make_float4(s0, s1, q0, q1);
    __syncthreads();
    if (t < 128) {
        float4 a = sh[t], b = sh[t + 128];
        sh[t] = make_float4(a.x + b.x, a.y + b.y, a.z + b.z, a.w + b.w);
    }
    __syncthreads();
    if (t < 64) {
        float4 a = sh[t], b = sh[t + 64];
        float* ps = pstats + (size_t)blockIdx.x * 256;
        ps[2 * t] = a.x + b.x;
        ps[2 * t + 1] = a.y + b.y;
        ps[128 + 2 * t] = a.z + b.z;
        ps[128 + 2 * t + 1] = a.w + b.w;
    }
}

// ---------------- stats reduction: pstats[3125][256] -> stats[256] --------

__global__ __launch_bounds__(256) void red_k(const float* __restrict__ pstats,
                                             float* __restrict__ stats) {
    int t = threadIdx.x;
    float s = 0.f;
    for (int r = blockIdx.x; r < AGG_BLOCKS; r += 64)
        s += pstats[(size_t)r * 256 + t];
    atomicAdd(&stats[t], s);
}

// ---------------- head tail: out += relu(gn2(x2)) @ Wh[128:256] -----------

__global__ __launch_bounds__(256) void final2_k(const uint32* __restrict__ x2,
                                                const float* __restrict__ stats,
                                                const float* __restrict__ gw,
                                                const float* __restrict__ gb,
                                                const float* __restrict__ ga,
                                                const float* __restrict__ Wh,
                                                float* __restrict__ out) {
    __shared__ float wl[128][16];
    __shared__ float parL[256];
    int t = threadIdx.x;
    if (t < 128) {
        float m = stats[t] * (1.0f / NN);
        float ex2 = stats[128 + t] * (1.0f / NN);
        float ac = ga[t];
        float var = ex2 - 2.0f * ac * m * m + ac * ac * m * m;
        float sc = gw[t] * rsqrtf(var + 1e-5f);
        parL[t] = sc;
        parL[128 + t] = gb[t] - sc * ac * m;
    }
    for (int i = t; i < 128 * 16; i += 256) wl[i >> 4][i & 15] = Wh[128 * 16 + i];
    __syncthreads();
    int row = blockIdx.x * 16 + (t >> 4);    // 6250*16 == NN exactly
    int o = t & 15;
    const uint4* x2p = (const uint4*)(x2 + (size_t)row * 64);
    float acc = out[(size_t)row * 16 + o];
#pragma unroll
    for (int k8 = 0; k8 < 16; ++k8) {
        uint4 u = x2p[k8];
        int c = k8 * 8;
        float v0 = bflo(u.x), v1 = bfhi(u.x);
        float v2 = bflo(u.y), v3 = bfhi(u.y);
        float v4 = bflo(u.z), v5 = bfhi(u.z);
        float v6 = bflo(u.w), v7 = bfhi(u.w);
        v0 = fmaxf(0.f, fmaf(parL[c + 0], v0, parL[128 + c + 0]));
        v1 = fmaxf(0.f, fmaf(parL[c + 1], v1, parL[128 + c + 1]));
        v2 = fmaxf(0.f, fmaf(parL[c + 2], v2, parL[128 + c + 2]));
        v3 = fmaxf(0.f, fmaf(parL[c + 3], v3, parL[128 + c + 3]));
        v4 = fmaxf(0.f, fmaf(parL[c + 4], v4, parL[128 + c + 4]));
        v5 = fmaxf(0.f, fmaf(parL[c + 5], v5, parL[128 + c + 5]));
        v6 = fmaxf(0.f, fmaf(parL[c + 6], v6, parL[128 + c + 6]));
        v7 = fmaxf(0.f, fmaf(parL[c + 7], v7, parL[128 + c + 7]));
        acc = fmaf(v0, wl[c + 0][o], acc);
        acc = fmaf(v1, wl[c + 1][o], acc);
        acc = fmaf(v2, wl[c + 2][o], acc);
        acc = fmaf(v3, wl[c + 3][o], acc);
        acc = fmaf(v4, wl[c + 4][o], acc);
        acc = fmaf(v5, wl[c + 5][o], acc);
        acc = fmaf(v6, wl[c + 6][o], acc);
        acc = fmaf(v7, wl[c + 7][o], acc);
    }
    out[(size_t)row * 16 + o] = acc;
}

// ---------------- launch ----------------

extern "C" void kernel_launch(void* const* d_in, const int* in_sizes, int n_in,
                              void* d_out, int out_size, void* d_ws, size_t ws_size,
                              hipStream_t stream) {
    const float* x   = (const float*)d_in[0];
    const int*   ei  = (const int*)d_in[1];
    const float* W1  = (const float*)d_in[2];
    const float* b1  = (const float*)d_in[3];
    const float* g1w = (const float*)d_in[4];
    const float* g1b = (const float*)d_in[5];
    const float* g1a = (const float*)d_in[6];
    const float* W2  = (const float*)d_in[7];
    const float* b2  = (const float*)d_in[8];
    const float* g2w = (const float*)d_in[9];
    const float* g2b = (const float*)d_in[10];
    const float* g2a = (const float*)d_in[11];
    const float* Wh  = (const float*)d_in[12];
    const float* bh  = (const float*)d_in[13];
    const int* srcp = ei;        // edge_index row 0
    const int* dstp = ei + NE;   // edge_index row 1
    float* out = (float*)d_out;

    char* p = (char*)d_ws;
    auto take = [&](size_t bytes) { char* r = p; p += (bytes + 255) & ~(size_t)255; return r; };
    int*   histT  = (int*)take((size_t)256 * NBLK * 4);
    int*   boff2  = (int*)take((size_t)256 * NBLK * 4);
    int*   btot   = (int*)take(256 * 4);
    int*   bucket_base = (int*)take(257 * 4);
    uint32* ebuf  = (uint32*)take((size_t)NE * 4);
    int*   offs   = (int*)take((size_t)(NN + 1) * 4);
    uint32* csrc  = (uint32*)take((size_t)NE * 4);
    float* dinv   = (float*)take((size_t)NN * 4);
    float* pstats = (float*)take((size_t)AGG_BLOCKS * 256 * 4);
    float* stats1 = (float*)take(256 * 4);
    float* stats2 = (float*)take(256 * 4);
    uint32* wt1   = (uint32*)take((size_t)128 * 64 * 4);   // bf16 W1^T
    uint32* wt2   = (uint32*)take((size_t)128 * 64 * 4);   // bf16 W2^T
    uint32* bufH  = (uint32*)take((size_t)NN * 64 * 4);    // bf16 packed
    uint32* bufA  = (uint32*)take((size_t)NN * 64 * 4);    // bf16 packed

    hipMemsetAsync(stats1, 0, 256 * 4, stream);
    hipMemsetAsync(stats2, 0, 256 * 4, stream);

    // weight prep (tiny), then phase 1: gemm1 ∥ hist ∥ head x-half
    wprep_k<<<64, 256, 0, stream>>>(W1, W2, wt1, wt2);
    phase1_k<<<GEMM_BLOCKS + NBLK + FINX_BLOCKS, 256, 0, stream>>>(
        dstp, histT, x, wt1, bufH, Wh, bh, out);

    // CSR scans + scatter + per-bucket offs/dinv + ds-packed fill
    p2a_k<<<256, 256, 0, stream>>>(histT, boff2, btot);
    p2b_k<<<1, 256, 0, stream>>>(btot, bucket_base, offs);
    p3_scatter_k<<<NBLK, 256, 0, stream>>>(srcp, dstp, boff2, bucket_base, ebuf);
    p4a_k<<<NBUCK, 256, 0, stream>>>(ebuf, bucket_base, offs, dinv);
    p4b_k<<<NBUCK, 256, 0, stream>>>(ebuf, bucket_base, offs, dinv, csrc);

    // layer 1 aggregate (+stats), reduce
    aggregate_k<<<AGG_BLOCKS, 256, 0, stream>>>(bufH, offs, csrc, dinv, b1, bufA, pstats);
    red_k<<<64, 256, 0, stream>>>(pstats, stats1);

    // layer 2: h2 = relu(gn1(bufA)) @ W2 (gn1 in-block, unscaled), aggregate
    gemm2_k<<<GEMM_BLOCKS, 256, 0, stream>>>(bufA, wt2, stats1, g1w, g1b, g1a, bufH);
    aggregate_k<<<AGG_BLOCKS, 256, 0, stream>>>(bufH, offs, csrc, dinv, b2, bufA, pstats);
    red_k<<<64, 256, 0, stream>>>(pstats, stats2);

    // head tail: out += relu(gn2(bufA)) @ Wh[128:256] (gn2 in-block)
    final2_k<<<FINX_BLOCKS, 256, 0, stream>>>(bufA, stats2, g2w, g2b, g2a, Wh, out);
}

// Round 16
// 325.569 us; speedup vs baseline: 1.0540x; 1.0540x over previous
//
#include <hip/hip_runtime.h>

#define NN 100000
#define NE 1600000

#define EBLK 4096
#define NBLK 391            // ceil(NE/EBLK)
#define NBUCK 196           // ceil(NN/512), bucket = dst>>9
#define GEMM_BLOCKS 1563    // ceil(NN/64)
#define FINX_BLOCKS 6250    // NN/16
#define AGG_BLOCKS 3125     // 32 nodes per block (8 per wave)

typedef unsigned int uint32;
typedef __attribute__((ext_vector_type(8))) short bf16x8;
typedef __attribute__((ext_vector_type(4))) float f32x4;

__device__ inline unsigned short f2bf(float f) {
    uint32 u = __float_as_uint(f);
    u += 0x7FFFu + ((u >> 16) & 1u);      // round to nearest even
    return (unsigned short)(u >> 16);
}
__device__ inline float bflo(uint32 v) { return __uint_as_float(v << 16); }
__device__ inline float bfhi(uint32 v) { return __uint_as_float(v & 0xFFFF0000u); }
__device__ inline uint32 packbf(float a, float b) {
    return (uint32)f2bf(a) | ((uint32)f2bf(b) << 16);
}

__device__ inline int wave_incl_scan(int v) {   // 64-lane inclusive scan
#pragma unroll
    for (int d = 1; d < 64; d <<= 1) {
        int u = __shfl_up(v, d, 64);
        if ((threadIdx.x & 63) >= (unsigned)d) v += u;
    }
    return v;
}

// ---- phase 1 (3 roles): hist (391) ∥ head-x (6250) ∥ wprep (64) ----------
// All roles independent and resource-light (8 KB LDS, low VGPR).

__global__ __launch_bounds__(256) void phase1_k(const int* __restrict__ dst,
                                                int* __restrict__ histT,
                                                const float* __restrict__ X,
                                                const float* __restrict__ Wh,
                                                const float* __restrict__ bh,
                                                float* __restrict__ out,
                                                const float* __restrict__ W1,
                                                const float* __restrict__ W2,
                                                uint32* __restrict__ wt1,
                                                uint32* __restrict__ wt2) {
    __shared__ __align__(16) float lds[128 * 16];
    int t = threadIdx.x;
    if (blockIdx.x < NBLK) {
        int* h = (int*)lds;
        h[t] = 0;
        __syncthreads();
        int e0 = blockIdx.x * EBLK;
#pragma unroll
        for (int i = 0; i < EBLK / 256; ++i) {
            int e = e0 + i * 256 + t;
            if (e < NE) atomicAdd(&h[dst[e] >> 9], 1);
        }
        __syncthreads();
        histT[t * NBLK + blockIdx.x] = h[t];   // histT[bucket][blk]
    } else if (blockIdx.x < NBLK + FINX_BLOCKS) {
        // head x-half: out[row,o] = bh[o] + sum_k x[row,k] * Wh[k][o]
        int bid = blockIdx.x - NBLK;
        float (*wl)[16] = (float(*)[16])lds;   // 128 x 16
        for (int i = t; i < 128 * 16; i += 256) wl[i >> 4][i & 15] = Wh[i];
        __syncthreads();
        int row = bid * 16 + (t >> 4);         // 6250*16 == NN exactly
        int o = t & 15;
        const float4* xp = (const float4*)(X + (size_t)row * 128);
        float acc = bh[o];
#pragma unroll
        for (int k4 = 0; k4 < 32; ++k4) {
            float4 v = xp[k4];
            acc = fmaf(v.x, wl[k4 * 4 + 0][o], acc);
            acc = fmaf(v.y, wl[k4 * 4 + 1][o], acc);
            acc = fmaf(v.z, wl[k4 * 4 + 2][o], acc);
            acc = fmaf(v.w, wl[k4 * 4 + 3][o], acc);
        }
        out[(size_t)row * 16 + o] = acc;
    } else {
        // wprep: Wt[col][k] bf16-packed
        int id = (blockIdx.x - NBLK - FINX_BLOCKS) * 256 + t;   // 16384
        const float* W = (id < 8192) ? W1 : W2;
        uint32* Wt = (id < 8192) ? wt1 : wt2;
        int i = id & 8191;
        int col = i >> 6, ku = i & 63;
        float a = W[(2 * ku) * 128 + col];
        float b = W[(2 * ku + 1) * 128 + col];
        Wt[i] = packbf(a, b);
    }
}

// ---------------- GEMM: HS[N,128](bf16) = dinv * act(X) @ Wt --------------
// AFF=0: X f32 [N,128]. AFF=1: X packed bf16; GraphNorm par from stats.
// Both scale rows by dinv[row] in epilogue.
// Block: 256 thr / 4 waves, tile 64 rows x 128 cols, K=128 in 4 steps of 32.
// LDS: A [64][136] bf16 (17408 B) + Bt [128][136] bf16 (34816 B) = 52224 B.

template <int AFF>
__global__ __launch_bounds__(256) void gemm_k(const void* __restrict__ Xv,
                                              const uint32* __restrict__ Wt,
                                              const float* __restrict__ stats,
                                              const float* __restrict__ gw,
                                              const float* __restrict__ gb,
                                              const float* __restrict__ ga,
                                              const float* __restrict__ dinv,
                                              uint32* __restrict__ HS) {
    __shared__ __align__(16) char lds[52224];
    __shared__ float parL[256];
    const int APITCH = 272;               // bytes per A/B row (136 bf16)
    char* Ab = lds;
    char* Bb = lds + 17408;
    int t = threadIdx.x;
    int row0 = blockIdx.x * 64;

    if (AFF) {
        if (t < 128) {
            float m = stats[t] * (1.0f / NN);
            float ex2 = stats[128 + t] * (1.0f / NN);
            float ac = ga[t];
            float var = ex2 - 2.0f * ac * m * m + ac * ac * m * m;
            float sc = gw[t] * rsqrtf(var + 1e-5f);
            parL[t] = sc;
            parL[128 + t] = gb[t] - sc * ac * m;
        }
        __syncthreads();
    }

    // stage Bt: 128 rows x 16 uint4 (packed bf16 Wt)
    {
        uint4* src = (uint4*)Wt;
#pragma unroll
        for (int i = 0; i < 8; ++i) {
            int idx4 = i * 256 + t;          // 2048 uint4
            int r = idx4 >> 4, cu = idx4 & 15;
            *(uint4*)(Bb + r * APITCH + cu * 16) = src[r * 16 + cu];
        }
    }
    // stage A: 64 rows x 128 bf16
#pragma unroll
    for (int i = 0; i < 8; ++i) {
        int idx = i * 256 + t;               // 2048 quads of channels
        int r = idx >> 5, c4 = idx & 31;
        int row = row0 + r;
        float4 v = make_float4(0.f, 0.f, 0.f, 0.f);
        if (row < NN) {
            if (AFF) {
                uint2 u = *((const uint2*)((const uint32*)Xv + (size_t)row * 64) + c4);
                v.x = bflo(u.x); v.y = bfhi(u.x);
                v.z = bflo(u.y); v.w = bfhi(u.y);
                int c = c4 * 4;
                v.x = fmaxf(0.f, fmaf(parL[c + 0], v.x, parL[128 + c + 0]));
                v.y = fmaxf(0.f, fmaf(parL[c + 1], v.y, parL[128 + c + 1]));
                v.z = fmaxf(0.f, fmaf(parL[c + 2], v.z, parL[128 + c + 2]));
                v.w = fmaxf(0.f, fmaf(parL[c + 3], v.w, parL[128 + c + 3]));
            } else {
                v = *((const float4*)((const float*)Xv + (size_t)row * 128) + c4);
            }
        }
        uint2 o;
        o.x = packbf(v.x, v.y);
        o.y = packbf(v.z, v.w);
        *(uint2*)(Ab + r * APITCH + c4 * 8) = o;
    }
    __syncthreads();

    int w = t >> 6, lane = t & 63;
    int l15 = lane & 15, l4 = lane >> 4;
    const char* aptr = Ab + (w * 16 + l15) * APITCH + l4 * 16;
    const char* bptr = Bb + l15 * APITCH + l4 * 16;
    f32x4 acc[8];
#pragma unroll
    for (int n = 0; n < 8; ++n)
#pragma unroll
        for (int j = 0; j < 4; ++j) acc[n][j] = 0.f;

#pragma unroll
    for (int ks = 0; ks < 4; ++ks) {
        bf16x8 a = *(const bf16x8*)(aptr + ks * 64);
#pragma unroll
        for (int n = 0; n < 8; ++n) {
            bf16x8 b = *(const bf16x8*)(bptr + n * 16 * APITCH + ks * 64);
            acc[n] = __builtin_amdgcn_mfma_f32_16x16x32_bf16(a, b, acc[n], 0, 0, 0);
        }
    }

    // epilogue: dinv scale -> bf16 -> LDS (reuse A region) -> coalesced store
    float dv[4];
    int rbase = row0 + w * 16 + l4 * 4;
#pragma unroll
    for (int j = 0; j < 4; ++j)
        dv[j] = (rbase + j < NN) ? dinv[rbase + j] : 0.f;
    unsigned short* ep = (unsigned short*)Ab;
#pragma unroll
    for (int n = 0; n < 8; ++n)
#pragma unroll
        for (int j = 0; j < 4; ++j)
            ep[(w * 16 + l4 * 4 + j) * 136 + n * 16 + l15] = f2bf(dv[j] * acc[n][j]);
    __syncthreads();
    int srow = lane >> 2, seg = lane & 3;
    int grow = row0 + w * 16 + srow;
    if (grow < NN) {
        const char* lp = Ab + (w * 16 + srow) * APITCH + seg * 64;
        uint4* gp = (uint4*)(HS + (size_t)grow * 64 + seg * 16);
#pragma unroll
        for (int i = 0; i < 4; ++i)
            gp[i] = *(const uint4*)(lp + i * 16);
    }
}

// ---------------- CSR build scans ----------------

__global__ __launch_bounds__(256) void p2a_k(const int* __restrict__ histT,
                                             int* __restrict__ boff2,
                                             int* __restrict__ btot) {
    __shared__ int ws[4];
    __shared__ int ws2[4];
    int b = blockIdx.x, t = threadIdx.x;
    const int* row = histT + (size_t)b * NBLK;
    int v0 = row[t];
    int i0 = wave_incl_scan(v0);
    if ((t & 63) == 63) ws[t >> 6] = i0;
    __syncthreads();
    int add = 0;
    for (int w = 0; w < (t >> 6); ++w) add += ws[w];
    boff2[(size_t)b * NBLK + t] = i0 - v0 + add;
    int tot0 = ws[0] + ws[1] + ws[2] + ws[3];
    int idx = 256 + t;
    int v1 = (idx < NBLK) ? row[idx] : 0;
    int i1 = wave_incl_scan(v1);
    if ((t & 63) == 63) ws2[t >> 6] = i1;
    __syncthreads();
    int add2 = 0;
    for (int w = 0; w < (t >> 6); ++w) add2 += ws2[w];
    if (idx < NBLK) boff2[(size_t)b * NBLK + idx] = tot0 + i1 - v1 + add2;
    if (t == 0) btot[b] = tot0 + ws2[0] + ws2[1] + ws2[2] + ws2[3];
}

__global__ __launch_bounds__(256) void p2b_k(const int* __restrict__ btot,
                                             int* __restrict__ bucket_base,
                                             int* __restrict__ offs) {
    __shared__ int ws[4];
    int t = threadIdx.x;
    int v = btot[t];
    int incl = wave_incl_scan(v);
    if ((t & 63) == 63) ws[t >> 6] = incl;
    __syncthreads();
    int add = 0;
    for (int w = 0; w < (t >> 6); ++w) add += ws[w];
    int excl = incl - v + add;
    bucket_base[t] = excl;
    if (t == 255) bucket_base[256] = excl + v;   // == NE
    if (t == 0) offs[NN] = NE;
}

__global__ __launch_bounds__(256) void p3_scatter_k(const int* __restrict__ src,
                                                    const int* __restrict__ dst,
                                                    const int* __restrict__ boff2,
                                                    const int* __restrict__ bucket_base,
                                                    uint32* __restrict__ ebuf) {
    __shared__ int cur[256];
    int t = threadIdx.x;
    cur[t] = bucket_base[t] + boff2[(size_t)t * NBLK + blockIdx.x];
    __syncthreads();
    int e0 = blockIdx.x * EBLK;
#pragma unroll
    for (int i = 0; i < EBLK / 256; ++i) {
        int e = e0 + i * 256 + t;
        if (e < NE) {
            int d = dst[e];
            int pos = atomicAdd(&cur[d >> 9], 1);      // LDS atomic
            ebuf[pos] = ((uint32)(d & 511) << 17) | (uint32)src[e];
        }
    }
}

__global__ __launch_bounds__(256) void p4_csr_k(const uint32* __restrict__ ebuf,
                                                const int* __restrict__ bucket_base,
                                                int* __restrict__ offs,
                                                float* __restrict__ dinv,
                                                int* __restrict__ csrc) {
    __shared__ int cntL[512];
    __shared__ int offL[512];
    __shared__ int wsum[4];
    int t = threadIdx.x;
    int bbase = bucket_base[blockIdx.x];
    int bend  = bucket_base[blockIdx.x + 1];
    cntL[t] = 0; cntL[t + 256] = 0;
    __syncthreads();
    for (int e = bbase + t; e < bend; e += 256)
        atomicAdd(&cntL[ebuf[e] >> 17], 1);
    __syncthreads();
    int c0 = cntL[2 * t], c1 = cntL[2 * t + 1];
    int ps = c0 + c1;
    int incl = wave_incl_scan(ps);
    if ((t & 63) == 63) wsum[t >> 6] = incl;
    __syncthreads();
    int add = 0;
    for (int w = 0; w < (t >> 6); ++w) add += wsum[w];
    int excl = incl - ps + add;
    offL[2 * t] = excl;
    offL[2 * t + 1] = excl + c0;
    int n0 = blockIdx.x * 512;
#pragma unroll
    for (int j = 0; j < 2; ++j) {
        int dl = 2 * t + j;
        int node = n0 + dl;
        if (node < NN) {
            offs[node] = bbase + offL[dl];
            dinv[node] = rsqrtf((float)(cntL[dl] + 1));
        }
    }
    __syncthreads();
    cntL[2 * t] = offL[2 * t];          // reuse as cursors
    cntL[2 * t + 1] = offL[2 * t + 1];
    __syncthreads();
    for (int e = bbase + t; e < bend; e += 256) {
        uint32 v = ebuf[e];
        int pos = atomicAdd(&cntL[v >> 17], 1);   // LDS atomic
        csrc[bbase + pos] = (int)(v & 0x1FFFFu);
    }
}

// ---------------- edge aggregation + fused GraphNorm stats ----------------
// hs rows pre-scaled by dinv:
// out[i,c] = dinv[i]*( sum_e hs[src,c] + hs[i,c] ) + bias[c]   (bf16 packed)
// One wave per node, 8 nodes sequentially per wave (32 nodes/block).
// Lane owns channels {2*lane, 2*lane+1}.
// MASKED full-width 16-batch: every iteration issues 16 independent gathers
// (OOB slots re-load csrc[beg]'s row -> L1-hot; weight 0 via wave-uniform
// scalar select). No 4/1 serial tails -> ceil(deg/16) latency units/node.

__global__ __launch_bounds__(256) void aggregate_k(const uint32* __restrict__ hv,
                                                   const int* __restrict__ offs,
                                                   const int* __restrict__ csrc,
                                                   const float* __restrict__ dinv,
                                                   const float* __restrict__ bias,
                                                   uint32* __restrict__ out,
                                                   float* __restrict__ pstats) {
    __shared__ float4 sh[256];
    int t = threadIdx.x;
    int w = t >> 6, lane = t & 63;
    int nbase = blockIdx.x * 32 + w * 8;
    float2 bb = ((const float2*)bias)[lane];
    float s0 = 0.f, s1 = 0.f, q0 = 0.f, q1 = 0.f;
#pragma unroll 1
    for (int i = 0; i < 8; ++i) {
        int node = nbase + i;
        int beg = offs[node], end = offs[node + 1];
        float di = dinv[node];
        uint32 sv = hv[(size_t)node * 64 + lane];   // self (pre-scaled)
        float a0 = bflo(sv), a1 = bfhi(sv);
#pragma unroll 1
        for (int e = beg; e < end; e += 16) {
            int idx[16];
            float mk[16];
#pragma unroll
            for (int k = 0; k < 16; ++k) {
                int ee = e + k;                 // wave-uniform
                idx[k] = (ee < end) ? ee : beg; // scalar select
                mk[k] = (ee < end) ? 1.0f : 0.0f;
            }
            uint32 vv[16];
#pragma unroll
            for (int k = 0; k < 16; ++k)
                vv[k] = hv[(size_t)csrc[idx[k]] * 64 + lane];
#pragma unroll
            for (int k = 0; k < 16; ++k) {
                a0 = fmaf(mk[k], bflo(vv[k]), a0);
                a1 = fmaf(mk[k], bfhi(vv[k]), a1);
            }
        }
        float o0 = fmaf(di, a0, bb.x);
        float o1 = fmaf(di, a1, bb.y);
        out[(size_t)node * 64 + lane] = packbf(o0, o1);
        s0 += o0; s1 += o1;
        q0 = fmaf(o0, o0, q0); q1 = fmaf(o1, o1, q1);
    }
    sh[t] = make_float4(s0, s1, q0, q1);
    __syncthreads();
    if (t < 128) {
        float4 a = sh[t], b = sh[t + 128];
        sh[t] = make_float4(a.x + b.x, a.y + b.y, a.z + b.z, a.w + b.w);
    }
    __syncthreads();
    if (t < 64) {
        float4 a = sh[t], b = sh[t + 64];
        float* ps = pstats + (size_t)blockIdx.x * 256;
        ps[2 * t] = a.x + b.x;
        ps[2 * t + 1] = a.y + b.y;
        ps[128 + 2 * t] = a.z + b.z;
        ps[128 + 2 * t + 1] = a.w + b.w;
    }
}

// ---------------- stats reduction: pstats[3125][256] -> stats[256] --------

__global__ __launch_bounds__(256) void red_k(const float* __restrict__ pstats,
                                             float* __restrict__ stats) {
    int t = threadIdx.x;
    float s = 0.f;
    for (int r = blockIdx.x; r < AGG_BLOCKS; r += 64)
        s += pstats[(size_t)r * 256 + t];
    atomicAdd(&stats[t], s);
}

// ---------------- head tail: out += relu(gn2(x2)) @ Wh[128:256] -----------

__global__ __launch_bounds__(256) void final2_k(const uint32* __restrict__ x2,
                                                const float* __restrict__ stats,
                                                const float* __restrict__ gw,
                                                const float* __restrict__ gb,
                                                const float* __restrict__ ga,
                                                const float* __restrict__ Wh,
                                                float* __restrict__ out) {
    __shared__ float wl[128][16];
    __shared__ float parL[256];
    int t = threadIdx.x;
    if (t < 128) {
        float m = stats[t] * (1.0f / NN);
        float ex2 = stats[128 + t] * (1.0f / NN);
        float ac = ga[t];
        float var = ex2 - 2.0f * ac * m * m + ac * ac * m * m;
        float sc = gw[t] * rsqrtf(var + 1e-5f);
        parL[t] = sc;
        parL[128 + t] = gb[t] - sc * ac * m;
    }
    for (int i = t; i < 128 * 16; i += 256) wl[i >> 4][i & 15] = Wh[128 * 16 + i];
    __syncthreads();
    int row = blockIdx.x * 16 + (t >> 4);    // 6250*16 == NN exactly
    int o = t & 15;
    const uint4* x2p = (const uint4*)(x2 + (size_t)row * 64);
    float acc = out[(size_t)row * 16 + o];
#pragma unroll
    for (int k8 = 0; k8 < 16; ++k8) {
        uint4 u = x2p[k8];
        int c = k8 * 8;
        float v0 = bflo(u.x), v1 = bfhi(u.x);
        float v2 = bflo(u.y), v3 = bfhi(u.y);
        float v4 = bflo(u.z), v5 = bfhi(u.z);
        float v6 = bflo(u.w), v7 = bfhi(u.w);
        v0 = fmaxf(0.f, fmaf(parL[c + 0], v0, parL[128 + c + 0]));
        v1 = fmaxf(0.f, fmaf(parL[c + 1], v1, parL[128 + c + 1]));
        v2 = fmaxf(0.f, fmaf(parL[c + 2], v2, parL[128 + c + 2]));
        v3 = fmaxf(0.f, fmaf(parL[c + 3], v3, parL[128 + c + 3]));
        v4 = fmaxf(0.f, fmaf(parL[c + 4], v4, parL[128 + c + 4]));
        v5 = fmaxf(0.f, fmaf(parL[c + 5], v5, parL[128 + c + 5]));
        v6 = fmaxf(0.f, fmaf(parL[c + 6], v6, parL[128 + c + 6]));
        v7 = fmaxf(0.f, fmaf(parL[c + 7], v7, parL[128 + c + 7]));
        acc = fmaf(v0, wl[c + 0][o], acc);
        acc = fmaf(v1, wl[c + 1][o], acc);
        acc = fmaf(v2, wl[c + 2][o], acc);
        acc = fmaf(v3, wl[c + 3][o], acc);
        acc = fmaf(v4, wl[c + 4][o], acc);
        acc = fmaf(v5, wl[c + 5][o], acc);
        acc = fmaf(v6, wl[c + 6][o], acc);
        acc = fmaf(v7, wl[c + 7][o], acc);
    }
    out[(size_t)row * 16 + o] = acc;
}

// ---------------- launch ----------------

extern "C" void kernel_launch(void* const* d_in, const int* in_sizes, int n_in,
                              void* d_out, int out_size, void* d_ws, size_t ws_size,
                              hipStream_t stream) {
    const float* x   = (const float*)d_in[0];
    const int*   ei  = (const int*)d_in[1];
    const float* W1  = (const float*)d_in[2];
    const float* b1  = (const float*)d_in[3];
    const float* g1w = (const float*)d_in[4];
    const float* g1b = (const float*)d_in[5];
    const float* g1a = (const float*)d_in[6];
    const float* W2  = (const float*)d_in[7];
    const float* b2  = (const float*)d_in[8];
    const float* g2w = (const float*)d_in[9];
    const float* g2b = (const float*)d_in[10];
    const float* g2a = (const float*)d_in[11];
    const float* Wh  = (const float*)d_in[12];
    const float* bh  = (const float*)d_in[13];
    const int* srcp = ei;        // edge_index row 0
    const int* dstp = ei + NE;   // edge_index row 1
    float* out = (float*)d_out;

    char* p = (char*)d_ws;
    auto take = [&](size_t bytes) { char* r = p; p += (bytes + 255) & ~(size_t)255; return r; };
    int*   histT  = (int*)take((size_t)256 * NBLK * 4);
    int*   boff2  = (int*)take((size_t)256 * NBLK * 4);
    int*   btot   = (int*)take(256 * 4);
    int*   bucket_base = (int*)take(257 * 4);
    uint32* ebuf  = (uint32*)take((size_t)NE * 4);
    int*   offs   = (int*)take((size_t)(NN + 1) * 4);
    int*   csrc   = (int*)take((size_t)NE * 4);
    float* dinv   = (float*)take((size_t)NN * 4);
    float* pstats = (float*)take((size_t)AGG_BLOCKS * 256 * 4);
    float* stats1 = (float*)take(256 * 4);
    float* stats2 = (float*)take(256 * 4);
    uint32* wt1   = (uint32*)take((size_t)128 * 64 * 4);   // bf16 W1^T
    uint32* wt2   = (uint32*)take((size_t)128 * 64 * 4);   // bf16 W2^T
    uint32* bufH  = (uint32*)take((size_t)NN * 64 * 4);    // bf16 packed
    uint32* bufA  = (uint32*)take((size_t)NN * 64 * 4);    // bf16 packed

    hipMemsetAsync(stats1, 0, 256 * 4, stream);
    hipMemsetAsync(stats2, 0, 256 * 4, stream);

    // phase 1: hist ∥ head x-half ∥ wprep (all resource-light)
    phase1_k<<<NBLK + FINX_BLOCKS + 64, 256, 0, stream>>>(
        dstp, histT, x, Wh, bh, out, W1, W2, wt1, wt2);

    // CSR scans + scatter + per-bucket fill
    p2a_k<<<256, 256, 0, stream>>>(histT, boff2, btot);
    p2b_k<<<1, 256, 0, stream>>>(btot, bucket_base, offs);
    p3_scatter_k<<<NBLK, 256, 0, stream>>>(srcp, dstp, boff2, bucket_base, ebuf);
    p4_csr_k<<<NBUCK, 256, 0, stream>>>(ebuf, bucket_base, offs, dinv, csrc);

    // layer 1: h1 = dinv * (x @ W1) (bf16 MFMA), aggregate+stats, reduce
    gemm_k<0><<<GEMM_BLOCKS, 256, 0, stream>>>(x, wt1, nullptr, nullptr, nullptr,
                                               nullptr, dinv, bufH);
    aggregate_k<<<AGG_BLOCKS, 256, 0, stream>>>(bufH, offs, csrc, dinv, b1, bufA, pstats);
    red_k<<<64, 256, 0, stream>>>(pstats, stats1);

    // layer 2: h2 = dinv * (relu(gn1(bufA)) @ W2) (gn1 in-block), aggregate
    gemm_k<1><<<GEMM_BLOCKS, 256, 0, stream>>>(bufA, wt2, stats1, g1w, g1b, g1a,
                                               dinv, bufH);
    aggregate_k<<<AGG_BLOCKS, 256, 0, stream>>>(bufH, offs, csrc, dinv, b2, bufA, pstats);
    red_k<<<64, 256, 0, stream>>>(pstats, stats2);

    // head tail: out += relu(gn2(bufA)) @ Wh[128:256] (gn2 in-block)
    final2_k<<<FINX_BLOCKS, 256, 0, stream>>>(bufA, stats2, g2w, g2b, g2a, Wh, out);
}